// Round 11
// baseline (488.402 us; speedup 1.0000x reference)
//
#include <hip/hip_runtime.h>
#include <hip/hip_bf16.h>
#include <stdint.h>

#define T_TOK 131072
#define DIM   512
#define NBR   8
#define ROWS  256                 // natural tokens per block
#define NBLK  (T_TOK / ROWS)      // 512 = 2 blocks/CU exactly
#define BK    32
#define NKT   (DIM / BK)          // 16
#define MAXSL 24                  // sum ceil(c_b/16) <= 8 + 256/16 - 1 = 23

typedef __attribute__((ext_vector_type(8))) __bf16 bf16x8;
typedef __attribute__((ext_vector_type(4))) float  f32x4;
typedef unsigned short ushort_t;

__device__ __forceinline__ unsigned short f2bf(float f) {
  union { float f; unsigned int u; } v; v.f = f;
  unsigned int r = v.u + 0x7fffu + ((v.u >> 16) & 1u);
  return (unsigned short)(r >> 16);
}

// ---------- W transpose: (N,D,D) f32 -> Wt bf16 [b][kt][col][kk] ----------
__global__ __launch_bounds__(256) void k_wtrans(const float* __restrict__ W,
                                                ushort_t* __restrict__ Wt) {
  __shared__ float tile[BK][129];
  int blk = blockIdx.x;          // 8 * 16 * 4 = 512 blocks
  int b  = blk >> 6;
  int kt = (blk >> 2) & 15;
  int cb = blk & 3;
  int t = threadIdx.x;
  #pragma unroll
  for (int i = 0; i < 4; ++i) {
    int idx4 = i * 256 + t;
    int kr = idx4 >> 5;
    int c4 = idx4 & 31;
    const float* src = W + (((size_t)b * DIM + (size_t)(kt * BK + kr)) * DIM + cb * 128 + c4 * 4);
    float4 v = *(const float4*)src;
    tile[kr][c4 * 4 + 0] = v.x;
    tile[kr][c4 * 4 + 1] = v.y;
    tile[kr][c4 * 4 + 2] = v.z;
    tile[kr][c4 * 4 + 3] = v.w;
  }
  __syncthreads();
  int c  = t >> 1;
  int kh = t & 1;
  unsigned int p[8];
  #pragma unroll
  for (int i = 0; i < 8; ++i) {
    unsigned short lo = f2bf(tile[kh * 16 + i * 2 + 0][c]);
    unsigned short hi = f2bf(tile[kh * 16 + i * 2 + 1][c]);
    p[i] = (unsigned int)lo | ((unsigned int)hi << 16);
  }
  size_t obase = (((size_t)b * 16 + kt) * DIM + (size_t)(cb * 128 + c)) * BK + kh * 16;
  uint4 q0; q0.x = p[0]; q0.y = p[1]; q0.z = p[2]; q0.w = p[3];
  uint4 q1; q1.x = p[4]; q1.y = p[5]; q1.z = p[6]; q1.w = p[7];
  *(uint4*)&Wt[obase]     = q0;
  *(uint4*)&Wt[obase + 8] = q1;
}

// ---------- fused: block-local sort + register-direct GEMM ----------
// Block = 256 natural tokens x 512 cols. 8 waves = 2 slice-groups x 4 col-groups.
// A-frags loaded DIRECTLY from x (16 rows x 128B full lines per instr-pair,
// inside the block's 512KB window). B from L2/L3-resident Wt. Epilogue writes
// 512B-contiguous row segments into the same window. LDS ~2KB; no barriers
// after the sort; 2 blocks/CU x 8 waves = 4 waves/SIMD.
__global__ __launch_bounds__(512, 4)
void k_fused(const float* __restrict__ x, const int* __restrict__ bidx,
             const ushort_t* __restrict__ Wt, const float* __restrict__ bias,
             float* __restrict__ out) {
  __shared__ int cnt[NBR], prefA[NBR];
  __shared__ int sliceBr[MAXSL], sliceBase[MAXSL], sliceLim[MAXSL];
  __shared__ short pmap[MAXSL * 16];
  __shared__ int tsL;

  const int t  = threadIdx.x;
  const int l  = t & 63;
  const int li = l & 15;
  const int c2 = l >> 4;
  const int wv = t >> 6;
  const int sgi = wv >> 2;            // slice-group 0..1
  const int cg  = wv & 3;             // col-group (128 cols)
  const int row0 = blockIdx.x * ROWS;

  // ---- local counting sort (16-aligned branch segments) ----
  if (t < NBR) cnt[t] = 0;
  if (t < MAXSL * 16) pmap[t] = 0;    // padded slots -> row 0 (read, never stored)
  __syncthreads();
  int myb = 0, myrank = 0;
  if (t < ROWS) {
    myb = bidx[row0 + t];
    myrank = atomicAdd(&cnt[myb], 1);
  }
  __syncthreads();
  if (t == 0) {
    int s = 0, ns = 0;
    for (int b = 0; b < NBR; ++b) {
      prefA[b] = s;
      int c = cnt[b];
      int nsl = (c + 15) >> 4;
      for (int o = 0; o < nsl; ++o) {
        sliceBase[ns] = s + o * 16; sliceBr[ns] = b; sliceLim[ns] = s + c; ++ns;
      }
      s += nsl * 16;
    }
    tsL = ns;
  }
  __syncthreads();
  if (t < ROWS) pmap[prefA[myb] + myrank] = (short)t;
  __syncthreads();
  const int nslice = tsL;

  const int boff0 = ((cg << 7) + li) * BK + c2 * 8;    // + cf*512
  const float* xb = x + (size_t)row0 * DIM;

  for (int sl = sgi; sl < nslice; sl += 2) {
    const int br    = sliceBr[sl];
    const int sbase = sliceBase[sl];
    const int slim  = sliceLim[sl];
    const int rA    = pmap[sbase + li];
    const float* aptr = xb + rA * DIM + c2 * 8;
    const ushort_t* wbase = Wt + (((size_t)br * NKT) << 14) + boff0;

    f32x4 acc[8];
    #pragma unroll
    for (int cf = 0; cf < 8; ++cf) acc[cf] = (f32x4){0.f, 0.f, 0.f, 0.f};

    float4 a0 = *(const float4*)(aptr);
    float4 a1 = *(const float4*)(aptr + 4);
    #pragma unroll
    for (int kt = 0; kt < NKT; ++kt) {
      bf16x8 bq[8];
      const ushort_t* wp = wbase + ((size_t)kt << 14);
      #pragma unroll
      for (int cf = 0; cf < 8; ++cf) bq[cf] = *(const bf16x8*)(wp + cf * 512);
      float4 n0, n1;
      if (kt + 1 < NKT) {               // depth-1 A prefetch (L2-hot window)
        n0 = *(const float4*)(aptr + (kt + 1) * BK);
        n1 = *(const float4*)(aptr + (kt + 1) * BK + 4);
      }
      union { ushort_t u[8]; bf16x8 v; } af;
      af.u[0] = f2bf(a0.x); af.u[1] = f2bf(a0.y);
      af.u[2] = f2bf(a0.z); af.u[3] = f2bf(a0.w);
      af.u[4] = f2bf(a1.x); af.u[5] = f2bf(a1.y);
      af.u[6] = f2bf(a1.z); af.u[7] = f2bf(a1.w);
      #pragma unroll
      for (int cf = 0; cf < 8; ++cf)
        acc[cf] = __builtin_amdgcn_mfma_f32_16x16x32_bf16(af.v, bq[cf], acc[cf], 0, 0, 0);
      if (kt + 1 < NKT) { a0 = n0; a1 = n1; }
    }

    // per-slice epilogue: 512B-contiguous per row, scattered within window
    float bv[8];
    #pragma unroll
    for (int cf = 0; cf < 8; ++cf)
      bv[cf] = bias[br * DIM + (cg << 7) + cf * 16 + li];
    #pragma unroll
    for (int j = 0; j < 4; ++j) {
      int slot = sbase + c2 * 4 + j;
      if (slot < slim) {
        int row = pmap[slot];
        float* op = out + (size_t)(row0 + row) * DIM + (cg << 7) + li;
        #pragma unroll
        for (int cf = 0; cf < 8; ++cf) op[cf * 16] = acc[cf][j] + bv[cf];
      }
    }
  }
}

// ---------------- launcher ----------------
// ws: [0,4MB) Wt bf16
extern "C" void kernel_launch(void* const* d_in, const int* in_sizes, int n_in,
                              void* d_out, int out_size, void* d_ws, size_t ws_size,
                              hipStream_t stream) {
  const float* x    = (const float*)d_in[0];
  const int*   bidx = (const int*)d_in[1];
  const float* W    = (const float*)d_in[2];
  const float* bias = (const float*)d_in[3];
  float* out = (float*)d_out;

  ushort_t* Wt = (ushort_t*)d_ws;

  k_wtrans<<<512, 256, 0, stream>>>(W, Wt);
  k_fused<<<NBLK, 512, 0, stream>>>(x, bidx, Wt, bias, out);
}